// Round 1
// baseline (308.266 us; speedup 1.0000x reference)
//
#include <hip/hip_runtime.h>
#include <hip/hip_fp8.h>
#include <stdint.h>

// x(4096x2048) @ W(2048x2048) + bias + probs, tanh.
static constexpr int MM = 4096;
static constexpr int KK = 2048;
static constexpr int NN = 2048;

typedef float floatx16 __attribute__((ext_vector_type(16)));
typedef __bf16 bf16x8 __attribute__((ext_vector_type(8)));
typedef unsigned short u16x8 __attribute__((ext_vector_type(8)));
typedef int intx4 __attribute__((ext_vector_type(4)));
typedef int intx8 __attribute__((ext_vector_type(8)));
typedef unsigned char u8x16 __attribute__((ext_vector_type(16)));

__device__ __forceinline__ unsigned short bf16_rne(float x) {
  union { float f; uint32_t u; } c; c.f = x;
  uint32_t u = c.u;
  u += 0x7fffu + ((u >> 16) & 1u);
  return (unsigned short)(u >> 16);
}
__device__ __forceinline__ float bf16_as_f32(unsigned short h) {
  union { float f; uint32_t u; } c; c.u = ((uint32_t)h) << 16;
  return c.f;
}
__device__ __forceinline__ unsigned char f32_to_e4m3(float x) {
  __hip_fp8_e4m3 q(x);           // OCP e4m3fn, RNE + saturate
  return (unsigned char)q.__x;
}
__device__ __forceinline__ float fast_tanh(float x) {
  float e = __expf(2.0f * x);
  return 1.0f - 2.0f / (e + 1.0f);
}
// bf16 (packed pair word) -> f32, exact (bf16 is truncated f32)
__device__ __forceinline__ float bflo(unsigned int w) {
  union { float f; unsigned u; } c; c.u = w << 16; return c.f;
}
__device__ __forceinline__ float bfhi(unsigned int w) {
  union { float f; unsigned u; } c; c.u = w & 0xffff0000u; return c.f;
}

// ---- Layouts -------------------------------------------------------------
// bf16 hi planes (UNCHANGED from verified R5): per row, 64-k groups of eight
// 16B chunks; phys8 = (c8 + row + (row>>3)) & 7.  Conflict-free.
//
// lo planes (NEW): per row, 64-k groups of four 16B chunks, contents
// PERMUTED to match the in-register-derived fp8 fragments (pi trick):
//   chunk c, byte b  <->  k = (c>>1)*32 + (b>>3)*16 + (c&1)*8 + (b&7)
// i.e. lane(half) reads chunks {half, 2+half} and gets exactly the k-set
// {s*16 + half*8 + j} its bf16 fragments cover -> same permutation pi on
// both MFMA operands => correct contraction.
// 4-slot swizzle: phys4 = (c + (row&3) + ((row>>2)&3)) & 3
// (verified: 8 accesses per 4-bank quad per wave = minimum cycles).

// ---- Fused pre-pass: blocks [0,2048) split x; [2048,3072) split W;
//      [3072,3080) probs+bias.
__global__ __launch_bounds__(256) void prepass_kernel(
    const float* __restrict__ x, const float* __restrict__ E,
    const float* __restrict__ W, const float* __restrict__ cb,
    unsigned short* __restrict__ ahi, unsigned char* __restrict__ al8,
    unsigned short* __restrict__ bhi, unsigned char* __restrict__ bl8,
    float* __restrict__ bias2) {
  __shared__ float tile[64][65];
  const int blk = blockIdx.x;
  const int tid = threadIdx.x;

  if (blk < 2048) {
    // ---- split x: one 16-elem unit per thread -------------------------
    int idx = blk * 256 + tid;
    int row = idx >> 7;        // 128 units per row
    int u = idx & 127;
    int g = u >> 2;            // 64-k group
    int q = u & 3;             // 16-k quarter within group
    const float4* s = (const float4*)(x + (size_t)row * KK + u * 16);
    float v[16];
#pragma unroll
    for (int p = 0; p < 4; p++) {
      float4 t = s[p];
      v[p * 4 + 0] = t.x; v[p * 4 + 1] = t.y; v[p * 4 + 2] = t.z; v[p * 4 + 3] = t.w;
    }
    unsigned short h[16];
    union { unsigned char b[16]; unsigned long long d[2]; } loq;
#pragma unroll
    for (int e = 0; e < 16; e++) {
      h[e] = bf16_rne(v[e]);
      float lo = v[e] - bf16_as_f32(h[e]);
      loq.b[e] = f32_to_e4m3(lo * 512.0f);
    }
    size_t rb = (size_t)row * KK;
#pragma unroll
    for (int cc = 0; cc < 2; cc++) {
      int c8 = q * 2 + cc;
      int phys8 = (c8 + row + (row >> 3)) & 7;
      u16x8 o;
#pragma unroll
      for (int e = 0; e < 8; e++) o[e] = h[cc * 8 + e];
      *(u16x8*)(ahi + rb + g * 64 + phys8 * 8) = o;
    }
    // lo: interleaved-chunk layout + 4-slot swizzle
    {
      int sw = (row & 3) + ((row >> 2) & 3);
      int cA = (q >> 1) * 2;
      char* lb = (char*)al8 + rb + g * 64;
      *(unsigned long long*)(lb + (((cA + 0) + sw) & 3) * 16 + (q & 1) * 8) = loq.d[0];
      *(unsigned long long*)(lb + (((cA + 1) + sw) & 3) * 16 + (q & 1) * 8) = loq.d[1];
    }
  } else if (blk < 3072) {
    // ---- transpose+split W --------------------------------------------
    const int wb = blk - 2048;
    const int n0 = (wb & 31) * 64;
    const int k0 = (wb >> 5) * 64;    // 64-aligned -> one swizzle group
#pragma unroll
    for (int i = 0; i < 4; i++) {
      int t = tid + i * 256;
      int kr = t >> 4;
      int nc = (t & 15) * 4;
      const float4 vv = *(const float4*)(W + (size_t)(k0 + kr) * NN + n0 + nc);
      tile[nc + 0][kr] = vv.x;
      tile[nc + 1][kr] = vv.y;
      tile[nc + 2][kr] = vv.z;
      tile[nc + 3][kr] = vv.w;
    }
    __syncthreads();
    const int nl = tid >> 2;       // 0..63 local n
    const int q = tid & 3;         // 16-k quarter
    const int n = n0 + nl;
    float v[16];
    unsigned short h[16];
    union { unsigned char b[16]; unsigned long long d[2]; } loq;
#pragma unroll
    for (int e = 0; e < 16; e++) {
      v[e] = tile[nl][q * 16 + e];
      h[e] = bf16_rne(v[e]);
      float lo = v[e] - bf16_as_f32(h[e]);
      loq.b[e] = f32_to_e4m3(lo * 512.0f);
    }
    size_t rb = (size_t)n * KK + k0;
#pragma unroll
    for (int cc = 0; cc < 2; cc++) {
      int c8 = q * 2 + cc;
      int phys8 = (c8 + n + (n >> 3)) & 7;
      u16x8 o;
#pragma unroll
      for (int e = 0; e < 8; e++) o[e] = h[cc * 8 + e];
      *(u16x8*)(bhi + rb + phys8 * 8) = o;
    }
    {
      int sw = (n & 3) + ((n >> 2) & 3);
      int cA = (q >> 1) * 2;
      char* lb = (char*)bl8 + rb;
      *(unsigned long long*)(lb + (((cA + 0) + sw) & 3) * 16 + (q & 1) * 8) = loq.d[0];
      *(unsigned long long*)(lb + (((cA + 1) + sw) & 3) * 16 + (q & 1) * 8) = loq.d[1];
    }
  } else {
    // ---- probs collapse (gate is translation-inv on uniform state) ----
    int i = (blk - 3072) * 256 + tid;
    if (i < NN) {
      float p = 1.0f / 2048.0f;
#pragma unroll
      for (int d = 0; d < 9; d++) {
        const float4 a = *(const float4*)(E + (size_t)d * (2048 * 2048) + (size_t)i * 2048);
        float c0 = cosf(a.x), c1 = cosf(a.y), c2 = cosf(a.z);
        p *= (c0 * c0) * (c1 * c1) * (c2 * c2);
      }
      bias2[i] = cb[i] + p;
    }
  }
}

// ---- Main GEMM ----------------------------------------------------------
// hi: bf16 32x32x16.  Corrections (al*b + a*bl): MX fp8 MFMA, full-value fp8
// operands DERIVED in-register from the bf16 fragments (pi-permutation),
// lo operands scaled by 2^-9 via E8M0 scale byte 0x76 -> accumulate straight
// into the main accumulator (no accc, no /512 epilogue).
// Pipeline: bf16 planes double-buffered, staged via counted vmcnt (never
// drained to 0 in-loop); lo planes single-buffered, latency hidden under the
// bf16 MFMA phase.  3 raw barriers/iter, no __syncthreads in the K-loop.
#define GLL(dst, src)                                                        \
  __builtin_amdgcn_global_load_lds(                                          \
      (const __attribute__((address_space(1))) void*)(src),                  \
      (__attribute__((address_space(3))) void*)(dst), 16, 0, 0)

__global__ __launch_bounds__(256, 2) void gemm_tanh_kernel(
    const unsigned short* __restrict__ Ahi, const unsigned char* __restrict__ Al8,
    const unsigned short* __restrict__ Bhi, const unsigned char* __restrict__ Bl8,
    const float* __restrict__ bias2, float* __restrict__ out) {
  __shared__ __align__(16) unsigned short sAh[2][128 * 64];  // 2 x 16 KB
  __shared__ __align__(16) unsigned short sBh[2][128 * 64];  // 2 x 16 KB
  __shared__ __align__(16) unsigned char sAl[128 * 64];      // 8 KB
  __shared__ __align__(16) unsigned char sBl[128 * 64];      // 8 KB
  // total 80 KB -> 2 blocks/CU (160 KB exactly)

  const int tid = threadIdx.x;
  const int lane = tid & 63;
  const int wave = tid >> 6;
  const int wm = (wave >> 1) * 64;   // wave: 64m x 64n as 2x2 of 32x32
  const int wn = (wave & 1) * 64;

  // 4x4 cluster swizzle: 16 consecutive block ids cover a 512m x 512n
  // super-tile -> shared A/B strips stay hot in the XCD L2s.
  const int id = blockIdx.x;         // 0..511
  const int cid = id >> 4, lid = id & 15;
  const int bm = ((cid >> 2) * 4 + (lid >> 2)) * 128;   // 32 m-blocks
  const int bn = ((cid & 3) * 4 + (lid & 3)) * 128;     // 16 n-blocks

  // bf16 staging: pass p -> rows 32p..32p+31; thread t: row t>>3, chunk t&7
  const size_t a16 = (size_t)(bm + (tid >> 3)) * KK + (tid & 7) * 8;
  const size_t b16 = (size_t)(bn + (tid >> 3)) * KK + (tid & 7) * 8;
  // lo staging: pass p -> rows 64p..64p+63; thread t: row t>>2, chunk t&3
  const size_t a8b = (size_t)(bm + (tid >> 2)) * KK + (tid & 3) * 16;
  const size_t b8b = (size_t)(bn + (tid >> 2)) * KK + (tid & 3) * 16;
  const int lds16 = tid * 8;   // ushort elements (= tid*16 B)
  const int lds8 = tid * 16;   // bytes

  const int r31 = lane & 31;
  const int half = lane >> 5;

  floatx16 acc[2][2];
#pragma unroll
  for (int i = 0; i < 2; i++)
#pragma unroll
    for (int j = 0; j < 2; j++)
#pragma unroll
      for (int r = 0; r < 16; r++) acc[i][j][r] = 0.f;

  // ---- prologue: stage bf16(k=0) into buffer 0 (8 loads in flight) ----
#pragma unroll
  for (int p = 0; p < 4; p++) {
    GLL(&sAh[0][p * 2048 + lds16], Ahi + a16 + (size_t)(32 * p) * KK);
    GLL(&sBh[0][p * 2048 + lds16], Bhi + b16 + (size_t)(32 * p) * KK);
  }

  for (int kt = 0; kt < 32; ++kt) {
    const int k0 = kt * 64;
    const int cur = kt & 1;
    const int nxt = cur ^ 1;

    __builtin_amdgcn_s_barrier();          // bar-A: prev compute fully done
    __builtin_amdgcn_sched_barrier(0);
    // lo(k): 4 loads (single buffer; latency hidden under bf16 phase)
#pragma unroll
    for (int p = 0; p < 2; p++) {
      GLL(&sAl[p * 4096 + lds8], Al8 + a8b + (size_t)k0 + (size_t)(64 * p) * KK);
      GLL(&sBl[p * 4096 + lds8], Bl8 + b8b + (size_t)k0 + (size_t)(64 * p) * KK);
    }
    // bf16(k+1): 8 loads into the other buffer (stay in flight across bars)
    const size_t kn = (kt < 31) ? (size_t)(k0 + 64) : 0;  // clamp: dummy last
#pragma unroll
    for (int p = 0; p < 4; p++) {
      GLL(&sAh[nxt][p * 2048 + lds16], Ahi + a16 + kn + (size_t)(32 * p) * KK);
      GLL(&sBh[nxt][p * 2048 + lds16], Bhi + b16 + kn + (size_t)(32 * p) * KK);
    }
    // wait: all but {lo(k):4, bf16(k+1):8} -> bf16(k) landed
    asm volatile("s_waitcnt vmcnt(12)" ::: "memory");
    __builtin_amdgcn_sched_barrier(0);
    __builtin_amdgcn_s_barrier();          // bar-B: bf16(k) visible to all
    __builtin_amdgcn_sched_barrier(0);

    // ---- bf16 phase: 4 x 16-k steps; derive fp8 full-value frags -------
    intx8 fa8[2], fb8[2];
#pragma unroll
    for (int s = 0; s < 4; s++) {
      const int c8 = s * 2 + half;
      bf16x8 fa[2], fb[2];
#pragma unroll
      for (int t = 0; t < 2; t++) {
        int rowA = wm + t * 32 + r31;
        int ao = rowA * 64 + ((c8 + rowA + (rowA >> 3)) & 7) * 8;
        fa[t] = *(const bf16x8*)(&sAh[cur][ao]);
        int rowB = wn + t * 32 + r31;
        int bo = rowB * 64 + ((c8 + rowB + (rowB >> 3)) & 7) * 8;
        fb[t] = *(const bf16x8*)(&sBh[cur][bo]);
      }
#pragma unroll
      for (int i = 0; i < 2; i++)
#pragma unroll
        for (int j = 0; j < 2; j++)
          acc[i][j] = __builtin_amdgcn_mfma_f32_32x32x16_bf16(fa[i], fb[j], acc[i][j], 0, 0, 0);
      // pack this step's 8 elems into fp8-frag dwords {2s, 2s+1}
#pragma unroll
      for (int t = 0; t < 2; t++) {
        uint4 ua = *(const uint4*)&fa[t];
        int d0 = __builtin_amdgcn_cvt_pk_fp8_f32(bflo(ua.x), bfhi(ua.x), 0, false);
        d0 = __builtin_amdgcn_cvt_pk_fp8_f32(bflo(ua.y), bfhi(ua.y), d0, true);
        int d1 = __builtin_amdgcn_cvt_pk_fp8_f32(bflo(ua.z), bfhi(ua.z), 0, false);
        d1 = __builtin_amdgcn_cvt_pk_fp8_f32(bflo(ua.w), bfhi(ua.w), d1, true);
        fa8[t][2 * s] = d0; fa8[t][2 * s + 1] = d1;
        uint4 ub = *(const uint4*)&fb[t];
        int e0 = __builtin_amdgcn_cvt_pk_fp8_f32(bflo(ub.x), bfhi(ub.x), 0, false);
        e0 = __builtin_amdgcn_cvt_pk_fp8_f32(bflo(ub.y), bfhi(ub.y), e0, true);
        int e1 = __builtin_amdgcn_cvt_pk_fp8_f32(bflo(ub.z), bfhi(ub.z), 0, false);
        e1 = __builtin_amdgcn_cvt_pk_fp8_f32(bflo(ub.w), bfhi(ub.w), e1, true);
        fb8[t][2 * s] = e0; fb8[t][2 * s + 1] = e1;
      }
    }

    // wait: all but {bf16(k+1):8} -> lo(k) landed
    asm volatile("s_waitcnt vmcnt(8)" ::: "memory");
    __builtin_amdgcn_sched_barrier(0);
    __builtin_amdgcn_s_barrier();          // bar-C: lo(k) visible to all
    __builtin_amdgcn_sched_barrier(0);

    // ---- fp8 correction phase: (al*2^9)*b*2^-9 + a*(bl*2^9)*2^-9 -------
    intx8 fal[2], fbl[2];
#pragma unroll
    for (int t = 0; t < 2; t++) {
      int rowA = wm + t * 32 + r31;
      int swA = (rowA & 3) + ((rowA >> 2) & 3);
      ((intx4*)&fal[t])[0] = *(const intx4*)(&sAl[rowA * 64 + ((half + swA) & 3) * 16]);
      ((intx4*)&fal[t])[1] = *(const intx4*)(&sAl[rowA * 64 + ((2 + half + swA) & 3) * 16]);
      int rowB = wn + t * 32 + r31;
      int swB = (rowB & 3) + ((rowB >> 2) & 3);
      ((intx4*)&fbl[t])[0] = *(const intx4*)(&sBl[rowB * 64 + ((half + swB) & 3) * 16]);
      ((intx4*)&fbl[t])[1] = *(const intx4*)(&sBl[rowB * 64 + ((2 + half + swB) & 3) * 16]);
    }
#pragma unroll
    for (int i = 0; i < 2; i++)
#pragma unroll
      for (int j = 0; j < 2; j++)
        acc[i][j] = __builtin_amdgcn_mfma_scale_f32_32x32x64_f8f6f4(
            fal[i], fb8[j], acc[i][j], 0, 0, 0, 0x76767676, 0, 0x7f7f7f7f);
#pragma unroll
    for (int i = 0; i < 2; i++)
#pragma unroll
      for (int j = 0; j < 2; j++)
        acc[i][j] = __builtin_amdgcn_mfma_scale_f32_32x32x64_f8f6f4(
            fa8[i], fbl[j], acc[i][j], 0, 0, 0, 0x7f7f7f7f, 0, 0x76767676);
  }

  // 32x32 C/D layout: col=lane&31, row=(reg&3)+8*(reg>>2)+4*(lane>>5)
#pragma unroll
  for (int j = 0; j < 2; j++) {
    int col = bn + wn + j * 32 + r31;
    float b2 = bias2[col];
#pragma unroll
    for (int i = 0; i < 2; i++) {
      int row0 = bm + wm + i * 32 + 4 * half;
#pragma unroll
      for (int r = 0; r < 16; r++) {
        int row = row0 + (r & 3) + 8 * (r >> 2);
        float val = acc[i][j][r] + b2;
        __builtin_nontemporal_store(fast_tanh(val), &out[(size_t)row * NN + col]);
      }
    }
  }
}

// ---- Fallback (ws too small): naive fp32 ---------------------------------
__global__ __launch_bounds__(256) void fallback_gemm(
    const float* __restrict__ x, const float* __restrict__ E,
    const float* __restrict__ W, const float* __restrict__ cb,
    float* __restrict__ out) {
  __shared__ float sA[16][16];
  __shared__ float sB[16][17];
  __shared__ float sbias[16];
  const int tx = threadIdx.x, ty = threadIdx.y;
  const int row = blockIdx.y * 16 + ty;
  const int col = blockIdx.x * 16 + tx;
  if (ty == 0) {
    float p = 1.0f / 2048.0f;
    for (int d = 0; d < 9; d++) {
      const float* a = E + (size_t)d * (2048 * 2048) + (size_t)col * 2048;
      for (int t = 0; t < 3; t++) { float c = cosf(a[t]); p *= c * c; }
    }
    sbias[tx] = p + cb[col];
  }
  float acc = 0.f;
  for (int k0 = 0; k0 < KK; k0 += 16) {
    __syncthreads();
    sA[ty][tx] = x[(size_t)row * KK + k0 + tx];
    sB[ty][tx] = W[(size_t)(k0 + ty) * NN + col];
    __syncthreads();
#pragma unroll
    for (int kk = 0; kk < 16; kk++) acc += sA[ty][kk] * sB[kk][tx];
  }
  out[(size_t)row * NN + col] = tanhf(acc + sbias[tx]);
}

extern "C" void kernel_launch(void* const* d_in, const int* in_sizes, int n_in,
                              void* d_out, int out_size, void* d_ws, size_t ws_size,
                              hipStream_t stream) {
  const float* x  = (const float*)d_in[0];
  const float* E  = (const float*)d_in[1];  // eternal_weights (9,2048,2048)
  const float* W  = (const float*)d_in[3];  // classical_weights (2048,2048)
  const float* cb = (const float*)d_in[4];  // classical_biases (2048,)
  float* out = (float*)d_out;

  const size_t MB = 1024 * 1024;
  const size_t need = 36 * MB + NN * sizeof(float);
  if (ws_size < need) {
    fallback_gemm<<<dim3(NN / 16, MM / 16), dim3(16, 16), 0, stream>>>(x, E, W, cb, out);
    return;
  }

  char* ws = (char*)d_ws;
  unsigned short* Ahi = (unsigned short*)(ws);            // 16 MB
  unsigned short* Bhi = (unsigned short*)(ws + 16 * MB);  //  8 MB
  unsigned char* Al8  = (unsigned char*)(ws + 24 * MB);   //  8 MB
  unsigned char* Bl8  = (unsigned char*)(ws + 32 * MB);   //  4 MB
  float* bias2 = (float*)(ws + 36 * MB);                  //  8 KB

  prepass_kernel<<<dim3(3080), dim3(256), 0, stream>>>(
      x, E, W, cb, Ahi, Al8, Bhi, Bl8, bias2);
  gemm_tanh_kernel<<<dim3(512), dim3(256), 0, stream>>>(
      Ahi, Al8, Bhi, Bl8, bias2, out);
}

// Round 2
// 294.972 us; speedup vs baseline: 1.0451x; 1.0451x over previous
//
#include <hip/hip_runtime.h>
#include <hip/hip_fp8.h>
#include <stdint.h>

// x(4096x2048) @ W(2048x2048) + bias + probs, tanh.
static constexpr int MM = 4096;
static constexpr int KK = 2048;
static constexpr int NN = 2048;

typedef float floatx16 __attribute__((ext_vector_type(16)));
typedef _Float16 f16x8 __attribute__((ext_vector_type(8)));
typedef unsigned short u16x8 __attribute__((ext_vector_type(8)));
typedef int intx4 __attribute__((ext_vector_type(4)));
typedef int intx8 __attribute__((ext_vector_type(8)));

__device__ __forceinline__ unsigned char f32_to_e4m3(float x) {
  __hip_fp8_e4m3 q(x);           // OCP e4m3fn, RNE + saturate
  return (unsigned char)q.__x;
}
__device__ __forceinline__ float fast_tanh(float x) {
  float e = __expf(2.0f * x);
  return 1.0f - 2.0f / (e + 1.0f);
}
__device__ __forceinline__ unsigned short f32_to_f16_bits(float x) {
  union { _Float16 h; unsigned short u; } c; c.h = (_Float16)x;  // RNE
  return c.u;
}
__device__ __forceinline__ float f16_bits_to_f32(unsigned short u) {
  union { _Float16 h; unsigned short u; } c; c.u = u;
  return (float)c.h;
}

// ---- Layouts -------------------------------------------------------------
// hi plane is now FP16 (not bf16): same 2B footprint, 3 extra mantissa bits,
// and crucially bf8-e5m2 == high byte of fp16 (same exponent bias 15), so the
// full-value fp8 operand for the correction MFMAs is derived in-register with
// ONE v_perm per 4 elements (R1's cvt_pk chain was 6x more VALU).
//
// hi plane: per row, 64-k groups of eight 16B chunks;
//   phys8 = (c8 + row + (row>>3)) & 7.  (verified conflict-free)
// lo plane (e4m3 of (x - fp16(x)) * 2^11): per row, 64-k groups of four 16B
// chunks, contents permuted to match the derived fragments (pi trick):
//   chunk c, byte b <-> k = (c>>1)*32 + (b>>3)*16 + (c&1)*8 + (b&7)
//   phys4 = (c + (row&3) + ((row>>2)&3)) & 3   (uniform 8 lanes/16B-slot)

// ---- Fused pre-pass: blocks [0,2048) split x; [2048,3072) split W;
//      [3072,3080) probs+bias.
__global__ __launch_bounds__(256) void prepass_kernel(
    const float* __restrict__ x, const float* __restrict__ E,
    const float* __restrict__ W, const float* __restrict__ cb,
    unsigned short* __restrict__ ahi, unsigned char* __restrict__ al8,
    unsigned short* __restrict__ bhi, unsigned char* __restrict__ bl8,
    float* __restrict__ bias2) {
  __shared__ float tile[64][65];
  const int blk = blockIdx.x;
  const int tid = threadIdx.x;

  if (blk < 2048) {
    // ---- split x: one 16-elem unit per thread -------------------------
    int idx = blk * 256 + tid;
    int row = idx >> 7;        // 128 units per row
    int u = idx & 127;
    int g = u >> 2;            // 64-k group
    int q = u & 3;             // 16-k quarter within group
    const float4* s = (const float4*)(x + (size_t)row * KK + u * 16);
    float v[16];
#pragma unroll
    for (int p = 0; p < 4; p++) {
      float4 t = s[p];
      v[p * 4 + 0] = t.x; v[p * 4 + 1] = t.y; v[p * 4 + 2] = t.z; v[p * 4 + 3] = t.w;
    }
    unsigned short h[16];
    union { unsigned char b[16]; unsigned long long d[2]; } loq;
#pragma unroll
    for (int e = 0; e < 16; e++) {
      h[e] = f32_to_f16_bits(v[e]);
      float lo = v[e] - f16_bits_to_f32(h[e]);
      loq.b[e] = f32_to_e4m3(lo * 2048.0f);
    }
    size_t rb = (size_t)row * KK;
#pragma unroll
    for (int cc = 0; cc < 2; cc++) {
      int c8 = q * 2 + cc;
      int phys8 = (c8 + row + (row >> 3)) & 7;
      u16x8 o;
#pragma unroll
      for (int e = 0; e < 8; e++) o[e] = h[cc * 8 + e];
      *(u16x8*)(ahi + rb + g * 64 + phys8 * 8) = o;
    }
    {
      int sw = (row & 3) + ((row >> 2) & 3);
      int cA = (q >> 1) * 2;
      char* lb = (char*)al8 + rb + g * 64;
      *(unsigned long long*)(lb + (((cA + 0) + sw) & 3) * 16 + (q & 1) * 8) = loq.d[0];
      *(unsigned long long*)(lb + (((cA + 1) + sw) & 3) * 16 + (q & 1) * 8) = loq.d[1];
    }
  } else if (blk < 3072) {
    // ---- transpose+split W --------------------------------------------
    const int wb = blk - 2048;
    const int n0 = (wb & 31) * 64;
    const int k0 = (wb >> 5) * 64;    // 64-aligned -> one swizzle group
#pragma unroll
    for (int i = 0; i < 4; i++) {
      int t = tid + i * 256;
      int kr = t >> 4;
      int nc = (t & 15) * 4;
      const float4 vv = *(const float4*)(W + (size_t)(k0 + kr) * NN + n0 + nc);
      tile[nc + 0][kr] = vv.x;
      tile[nc + 1][kr] = vv.y;
      tile[nc + 2][kr] = vv.z;
      tile[nc + 3][kr] = vv.w;
    }
    __syncthreads();
    const int nl = tid >> 2;       // 0..63 local n
    const int q = tid & 3;         // 16-k quarter
    const int n = n0 + nl;
    float v[16];
    unsigned short h[16];
    union { unsigned char b[16]; unsigned long long d[2]; } loq;
#pragma unroll
    for (int e = 0; e < 16; e++) {
      v[e] = tile[nl][q * 16 + e];
      h[e] = f32_to_f16_bits(v[e]);
      float lo = v[e] - f16_bits_to_f32(h[e]);
      loq.b[e] = f32_to_e4m3(lo * 2048.0f);
    }
    size_t rb = (size_t)n * KK + k0;
#pragma unroll
    for (int cc = 0; cc < 2; cc++) {
      int c8 = q * 2 + cc;
      int phys8 = (c8 + n + (n >> 3)) & 7;
      u16x8 o;
#pragma unroll
      for (int e = 0; e < 8; e++) o[e] = h[cc * 8 + e];
      *(u16x8*)(bhi + rb + phys8 * 8) = o;
    }
    {
      int sw = (n & 3) + ((n >> 2) & 3);
      int cA = (q >> 1) * 2;
      char* lb = (char*)bl8 + rb;
      *(unsigned long long*)(lb + (((cA + 0) + sw) & 3) * 16 + (q & 1) * 8) = loq.d[0];
      *(unsigned long long*)(lb + (((cA + 1) + sw) & 3) * 16 + (q & 1) * 8) = loq.d[1];
    }
  } else {
    // ---- probs collapse (gate is translation-inv on uniform state) ----
    int i = (blk - 3072) * 256 + tid;
    if (i < NN) {
      float p = 1.0f / 2048.0f;
#pragma unroll
      for (int d = 0; d < 9; d++) {
        const float4 a = *(const float4*)(E + (size_t)d * (2048 * 2048) + (size_t)i * 2048);
        float c0 = cosf(a.x), c1 = cosf(a.y), c2 = cosf(a.z);
        p *= (c0 * c0) * (c1 * c1) * (c2 * c2);
      }
      bias2[i] = cb[i] + p;
    }
  }
}

// ---- Main GEMM ----------------------------------------------------------
// hi: f16 32x32x16.  Corrections (al*b + a*bl): MX fp8 MFMA; full-value
// operand = e5m2 byte-truncation of the f16 fragments (v_perm, ~free); lo
// operand e4m3 scaled 2^-11 via E8M0 byte 0x74 -> accumulate into main acc.
// All LDS read addresses hoisted (kt-invariant); K-loop unrolled x2 so the
// double-buffer base is a compile-time immediate.  Counted vmcnt pipeline
// (never drained in-loop), 3 raw barriers/iter, setprio around MFMA.
#define GLL(dst, src)                                                        \
  __builtin_amdgcn_global_load_lds(                                          \
      (const __attribute__((address_space(1))) void*)(src),                  \
      (__attribute__((address_space(3))) void*)(dst), 16, 0, 0)

#define BODY(CUR, NXT, KLO, KNX)                                               \
  {                                                                            \
    __builtin_amdgcn_s_barrier();                                              \
    __builtin_amdgcn_sched_barrier(0);                                         \
    _Pragma("unroll") for (int p = 0; p < 2; p++) {                            \
      GLL(&sAl[p * 4096 + lds8], Al8 + a8b + (size_t)(KLO) + (size_t)(64 * p) * KK); \
      GLL(&sBl[p * 4096 + lds8], Bl8 + b8b + (size_t)(KLO) + (size_t)(64 * p) * KK); \
    }                                                                          \
    _Pragma("unroll") for (int p = 0; p < 4; p++) {                            \
      GLL(&sAh[NXT][p * 2048 + lds16], Ahi + a16 + (size_t)(KNX) + (size_t)(32 * p) * KK); \
      GLL(&sBh[NXT][p * 2048 + lds16], Bhi + b16 + (size_t)(KNX) + (size_t)(32 * p) * KK); \
    }                                                                          \
    asm volatile("s_waitcnt vmcnt(12)" ::: "memory");                          \
    __builtin_amdgcn_sched_barrier(0);                                         \
    __builtin_amdgcn_s_barrier();                                              \
    __builtin_amdgcn_sched_barrier(0);                                         \
    intx8 fa8[2], fb8[2];                                                      \
    __builtin_amdgcn_s_setprio(1);                                             \
    _Pragma("unroll") for (int s = 0; s < 4; s++) {                            \
      f16x8 fa[2], fb[2];                                                      \
      _Pragma("unroll") for (int t = 0; t < 2; t++) {                          \
        fa[t] = *(const f16x8*)(sAhB + (CUR) * 16384 + aho[s][t]);             \
        fb[t] = *(const f16x8*)(sBhB + (CUR) * 16384 + bho[s][t]);             \
      }                                                                        \
      _Pragma("unroll") for (int i = 0; i < 2; i++)                            \
        _Pragma("unroll") for (int j = 0; j < 2; j++)                          \
          acc[i][j] = __builtin_amdgcn_mfma_f32_32x32x16_f16(fa[i], fb[j], acc[i][j], 0, 0, 0); \
      _Pragma("unroll") for (int t = 0; t < 2; t++) {                          \
        const uint4 ua = *(const uint4*)&fa[t];                                \
        fa8[t][2 * s]     = (int)__builtin_amdgcn_perm(ua.y, ua.x, 0x07050301u); \
        fa8[t][2 * s + 1] = (int)__builtin_amdgcn_perm(ua.w, ua.z, 0x07050301u); \
        const uint4 ub = *(const uint4*)&fb[t];                                \
        fb8[t][2 * s]     = (int)__builtin_amdgcn_perm(ub.y, ub.x, 0x07050301u); \
        fb8[t][2 * s + 1] = (int)__builtin_amdgcn_perm(ub.w, ub.z, 0x07050301u); \
      }                                                                        \
    }                                                                          \
    __builtin_amdgcn_s_setprio(0);                                             \
    asm volatile("s_waitcnt vmcnt(8)" ::: "memory");                           \
    __builtin_amdgcn_sched_barrier(0);                                         \
    __builtin_amdgcn_s_barrier();                                              \
    __builtin_amdgcn_sched_barrier(0);                                         \
    intx8 fal[2], fbl[2];                                                      \
    _Pragma("unroll") for (int t = 0; t < 2; t++) {                            \
      ((intx4*)&fal[t])[0] = *(const intx4*)(sAlB + alo[t][0]);                \
      ((intx4*)&fal[t])[1] = *(const intx4*)(sAlB + alo[t][1]);                \
      ((intx4*)&fbl[t])[0] = *(const intx4*)(sBlB + blo[t][0]);                \
      ((intx4*)&fbl[t])[1] = *(const intx4*)(sBlB + blo[t][1]);                \
    }                                                                          \
    __builtin_amdgcn_s_setprio(1);                                             \
    _Pragma("unroll") for (int i = 0; i < 2; i++)                              \
      _Pragma("unroll") for (int j = 0; j < 2; j++)                            \
        acc[i][j] = __builtin_amdgcn_mfma_scale_f32_32x32x64_f8f6f4(           \
            fal[i], fb8[j], acc[i][j], 0, 1, 0, 0x74747474, 0, 0x7f7f7f7f);    \
    _Pragma("unroll") for (int i = 0; i < 2; i++)                              \
      _Pragma("unroll") for (int j = 0; j < 2; j++)                            \
        acc[i][j] = __builtin_amdgcn_mfma_scale_f32_32x32x64_f8f6f4(           \
            fa8[i], fbl[j], acc[i][j], 1, 0, 0, 0x7f7f7f7f, 0, 0x74747474);    \
    __builtin_amdgcn_s_setprio(0);                                             \
  }

__global__ __launch_bounds__(256, 2) void gemm_tanh_kernel(
    const unsigned short* __restrict__ Ahi, const unsigned char* __restrict__ Al8,
    const unsigned short* __restrict__ Bhi, const unsigned char* __restrict__ Bl8,
    const float* __restrict__ bias2, float* __restrict__ out) {
  __shared__ __align__(16) unsigned short sAh[2][8192];  // 32 KB
  __shared__ __align__(16) unsigned short sBh[2][8192];  // 32 KB
  __shared__ __align__(16) unsigned char sAl[8192];      //  8 KB
  __shared__ __align__(16) unsigned char sBl[8192];      //  8 KB
  // total 80 KB -> 2 blocks/CU (160 KB exactly)

  const int tid = threadIdx.x;
  const int lane = tid & 63;
  const int wave = tid >> 6;
  const int wm = (wave >> 1) * 64;   // wave: 64m x 64n as 2x2 of 32x32
  const int wn = (wave & 1) * 64;

  // 4x4 cluster swizzle: 16 consecutive block ids cover a 512m x 512n
  // super-tile -> shared A/B strips stay hot in the XCD L2s.
  const int id = blockIdx.x;         // 0..511
  const int cid = id >> 4, lid = id & 15;
  const int bm = ((cid >> 2) * 4 + (lid >> 2)) * 128;   // 32 m-blocks
  const int bn = ((cid & 3) * 4 + (lid & 3)) * 128;     // 16 n-blocks

  // hi staging: pass p -> rows 32p..32p+31; thread t: row t>>3, chunk t&7
  const size_t a16 = (size_t)(bm + (tid >> 3)) * KK + (tid & 7) * 8;
  const size_t b16 = (size_t)(bn + (tid >> 3)) * KK + (tid & 7) * 8;
  // lo staging: pass p -> rows 64p..64p+63; thread t: row t>>2, chunk t&3
  const size_t a8b = (size_t)(bm + (tid >> 2)) * KK + (tid & 3) * 16;
  const size_t b8b = (size_t)(bn + (tid >> 2)) * KK + (tid & 3) * 16;
  const int lds16 = tid * 8;   // ushort elements (= tid*16 B)
  const int lds8 = tid * 16;   // bytes

  const int r31 = lane & 31;
  const int half = lane >> 5;

  // ---- hoisted, kt-invariant LDS read byte-offsets ----------------------
  const char* sAhB = (const char*)(&sAh[0][0]);
  const char* sBhB = (const char*)(&sBh[0][0]);
  const char* sAlB = (const char*)(&sAl[0]);
  const char* sBlB = (const char*)(&sBl[0]);
  int aho[4][2], bho[4][2];
#pragma unroll
  for (int s = 0; s < 4; s++)
#pragma unroll
    for (int t = 0; t < 2; t++) {
      const int rowA = wm + t * 32 + r31;
      aho[s][t] = rowA * 128 + ((2 * s + half + rowA + (rowA >> 3)) & 7) * 16;
      const int rowB = wn + t * 32 + r31;
      bho[s][t] = rowB * 128 + ((2 * s + half + rowB + (rowB >> 3)) & 7) * 16;
    }
  int alo[2][2], blo[2][2];
#pragma unroll
  for (int t = 0; t < 2; t++) {
    const int rowA = wm + t * 32 + r31;
    const int swA = (rowA & 3) + ((rowA >> 2) & 3);
    alo[t][0] = rowA * 64 + ((half + swA) & 3) * 16;
    alo[t][1] = rowA * 64 + ((2 + half + swA) & 3) * 16;
    const int rowB = wn + t * 32 + r31;
    const int swB = (rowB & 3) + ((rowB >> 2) & 3);
    blo[t][0] = rowB * 64 + ((half + swB) & 3) * 16;
    blo[t][1] = rowB * 64 + ((2 + half + swB) & 3) * 16;
  }

  floatx16 acc[2][2];
#pragma unroll
  for (int i = 0; i < 2; i++)
#pragma unroll
    for (int j = 0; j < 2; j++)
#pragma unroll
      for (int r = 0; r < 16; r++) acc[i][j][r] = 0.f;

  // ---- prologue: stage hi(k=0) into buffer 0 (8 loads in flight) --------
#pragma unroll
  for (int p = 0; p < 4; p++) {
    GLL(&sAh[0][p * 2048 + lds16], Ahi + a16 + (size_t)(32 * p) * KK);
    GLL(&sBh[0][p * 2048 + lds16], Bhi + b16 + (size_t)(32 * p) * KK);
  }

  for (int kt = 0; kt < 32; kt += 2) {
    const int k0 = kt * 64;
    BODY(0, 1, k0, k0 + 64)
    BODY(1, 0, k0 + 64, (kt < 30) ? (k0 + 128) : 0)
  }
  asm volatile("s_waitcnt vmcnt(0)" ::: "memory");

  // 32x32 C/D layout: col=lane&31, row=(reg&3)+8*(reg>>2)+4*(lane>>5)
#pragma unroll
  for (int j = 0; j < 2; j++) {
    int col = bn + wn + j * 32 + r31;
    float b2 = bias2[col];
#pragma unroll
    for (int i = 0; i < 2; i++) {
      int row0 = bm + wm + i * 32 + 4 * half;
#pragma unroll
      for (int r = 0; r < 16; r++) {
        int row = row0 + (r & 3) + 8 * (r >> 2);
        float val = acc[i][j][r] + b2;
        __builtin_nontemporal_store(fast_tanh(val), &out[(size_t)row * NN + col]);
      }
    }
  }
}

// ---- Fallback (ws too small): naive fp32 ---------------------------------
__global__ __launch_bounds__(256) void fallback_gemm(
    const float* __restrict__ x, const float* __restrict__ E,
    const float* __restrict__ W, const float* __restrict__ cb,
    float* __restrict__ out) {
  __shared__ float sA[16][16];
  __shared__ float sB[16][17];
  __shared__ float sbias[16];
  const int tx = threadIdx.x, ty = threadIdx.y;
  const int row = blockIdx.y * 16 + ty;
  const int col = blockIdx.x * 16 + tx;
  if (ty == 0) {
    float p = 1.0f / 2048.0f;
    for (int d = 0; d < 9; d++) {
      const float* a = E + (size_t)d * (2048 * 2048) + (size_t)col * 2048;
      for (int t = 0; t < 3; t++) { float c = cosf(a[t]); p *= c * c; }
    }
    sbias[tx] = p + cb[col];
  }
  float acc = 0.f;
  for (int k0 = 0; k0 < KK; k0 += 16) {
    __syncthreads();
    sA[ty][tx] = x[(size_t)row * KK + k0 + tx];
    sB[ty][tx] = W[(size_t)(k0 + ty) * NN + col];
    __syncthreads();
#pragma unroll
    for (int kk = 0; kk < 16; kk++) acc += sA[ty][kk] * sB[kk][tx];
  }
  out[(size_t)row * NN + col] = tanhf(acc + sbias[tx]);
}

extern "C" void kernel_launch(void* const* d_in, const int* in_sizes, int n_in,
                              void* d_out, int out_size, void* d_ws, size_t ws_size,
                              hipStream_t stream) {
  const float* x  = (const float*)d_in[0];
  const float* E  = (const float*)d_in[1];  // eternal_weights (9,2048,2048)
  const float* W  = (const float*)d_in[3];  // classical_weights (2048,2048)
  const float* cb = (const float*)d_in[4];  // classical_biases (2048,)
  float* out = (float*)d_out;

  const size_t MB = 1024 * 1024;
  const size_t need = 36 * MB + NN * sizeof(float);
  if (ws_size < need) {
    fallback_gemm<<<dim3(NN / 16, MM / 16), dim3(16, 16), 0, stream>>>(x, E, W, cb, out);
    return;
  }

  char* ws = (char*)d_ws;
  unsigned short* Ahi = (unsigned short*)(ws);            // 16 MB (fp16)
  unsigned short* Bhi = (unsigned short*)(ws + 16 * MB);  //  8 MB (fp16)
  unsigned char* Al8  = (unsigned char*)(ws + 24 * MB);   //  8 MB
  unsigned char* Bl8  = (unsigned char*)(ws + 32 * MB);   //  4 MB
  float* bias2 = (float*)(ws + 36 * MB);                  //  8 KB

  prepass_kernel<<<dim3(3080), dim3(256), 0, stream>>>(
      x, E, W, cb, Ahi, Al8, Bhi, Bl8, bias2);
  gemm_tanh_kernel<<<dim3(512), dim3(256), 0, stream>>>(
      Ahi, Al8, Bhi, Bl8, bias2, out);
}